// Round 4
// baseline (183.132 us; speedup 1.0000x reference)
//
#include <hip/hip_runtime.h>
#include <math.h>

#define NPTS  16384
#define KNN   16
#define SEQV  8
#define NW    16      // waves per block
#define BATCH 8
#define CAPM  15      // append words/thread (flush thr 7 -> max idx 14)
#define CAPR  1.001f  // radius cap in d2 space (d2>1 neighbors map to self)
#define NBKT  256
#define BSCALE 56.8888f   // NBKT / 4.5 norm range

// Transposed LDS slot: row t (0..15), column col (0..1023).
#define SLOT(arr, t, col) arr[(t) * 1024 + (col)]

// ws layout (bytes): accum 0..255 | hist 256.. | starts 1536.. | cursor 2816.. | sorted 4096..
#define WS_HIST   256
#define WS_STARTS 1536
#define WS_CURSOR 2816
#define WS_SORTED 4096

__device__ __forceinline__ unsigned umin_(unsigned a, unsigned b) { return a < b ? a : b; }
__device__ __forceinline__ unsigned umax_(unsigned a, unsigned b) { return a > b ? a : b; }

// norm -> bucket, monotone; shared by scatter & window math (consistency!)
__device__ __forceinline__ int nbucket(float x) { return (int)fminf(x * BSCALE, 255.0f); }

// merge one key into sorted ascending keys[16] (scan-path flushes only)
__device__ __forceinline__ void merge_one(unsigned keys[KNN], unsigned kk) {
    if (kk < keys[KNN - 1]) {
#pragma unroll
        for (int u = 0; u < KNN; ++u) {
            unsigned lo = umin_(kk, keys[u]);
            kk = umax_(kk, keys[u]);
            keys[u] = lo;
        }
    }
}

// Exact top-16 of two sorted-ascending 16-lists (bitonic, ~80 unpredicated ops)
__device__ __forceinline__ void merge16(unsigned k[KNN], const unsigned o[KNN]) {
    unsigned v[KNN];
#pragma unroll
    for (int i = 0; i < KNN; ++i) v[i] = umin_(k[i], o[KNN - 1 - i]);
#pragma unroll
    for (int d = 8; d >= 1; d >>= 1) {
#pragma unroll
        for (int i = 0; i < KNN; ++i) {
            if ((i & d) == 0) {
                unsigned lo = umin_(v[i], v[i + d]);
                unsigned hi = umax_(v[i], v[i + d]);
                v[i] = lo; v[i + d] = hi;
            }
        }
    }
#pragma unroll
    for (int i = 0; i < KNN; ++i) k[i] = v[i];
}

__device__ __forceinline__ void tree_load_merge(unsigned* uS, unsigned keys[KNN], int src) {
    unsigned o[KNN];
#pragma unroll
    for (int t = 0; t < KNN; ++t) o[t] = SLOT(uS, t, src);
    merge16(keys, o);
}

// ---------------------------------------------------------------------------
// K1: norm histogram (memset zeroes hist+accum beforehand)
// ---------------------------------------------------------------------------
__global__ void hist_kernel(const float* __restrict__ pc, unsigned* __restrict__ hist)
{
    const int i = blockIdx.x * 1024 + threadIdx.x;
    const float x = pc[3 * i + 0], y = pc[3 * i + 1], z = pc[3 * i + 2];
    const float n = sqrtf(fmaf(x, x, fmaf(y, y, z * z)));
    atomicAdd(&hist[nbucket(n)], 1u);
}

// ---------------------------------------------------------------------------
// K2: exclusive prefix over 256 bins (Hillis-Steele in LDS) -> starts, cursor
// ---------------------------------------------------------------------------
__global__ void prefix_kernel(const unsigned* __restrict__ hist,
                              unsigned* __restrict__ starts, unsigned* __restrict__ cursor)
{
    __shared__ unsigned s[NBKT];
    const int t = threadIdx.x;
    const unsigned h = hist[t];
    s[t] = h;
    __syncthreads();
    for (int off = 1; off < NBKT; off <<= 1) {
        unsigned a = (t >= off) ? s[t - off] : 0u;
        __syncthreads();
        s[t] += a;
        __syncthreads();
    }
    const unsigned excl = s[t] - h;
    starts[t] = excl; cursor[t] = excl;
    if (t == NBKT - 1) starts[NBKT] = s[t];
}

// ---------------------------------------------------------------------------
// K3: scatter into norm-bucketed order; w channel = original index bits.
// Pads [NPTS, NPTS+8): far sentinels (d2 -> ~3e36, never accepted).
// ---------------------------------------------------------------------------
__global__ void scatter_kernel(const float* __restrict__ pc,
                               unsigned* __restrict__ cursor, float4* __restrict__ sorted)
{
    const int i = blockIdx.x * 1024 + threadIdx.x;
    const float x = pc[3 * i + 0], y = pc[3 * i + 1], z = pc[3 * i + 2];
    const float n = sqrtf(fmaf(x, x, fmaf(y, y, z * z)));
    const unsigned pos = atomicAdd(&cursor[nbucket(n)], 1u);
    sorted[pos] = make_float4(x, y, z, __uint_as_float((unsigned)i));
    if (blockIdx.x == 0 && threadIdx.x < 8)
        sorted[NPTS + threadIdx.x] = make_float4(1e18f, 1e18f, 1e18f, __uint_as_float(0u));
}

// ---------------------------------------------------------------------------
// K4: windowed mega. Grid 256 x 1024; block = 64 norm-adjacent queries
// (lane = query), 16 waves share the block's candidate window.
// Triangle inequality: | |c|-|q| | > sqrt(tau) => d2 > tau, so only the
// norm-window needs scanning. Tau window uses r0 = sqrt(tau0) (cert-valid);
// Phase A re-windows with rA = sqrt(max certified tau) (much tighter).
// Keys carry ORIGINAL indices -> selection/tie-break identical to round 3.
// ---------------------------------------------------------------------------
__global__ __launch_bounds__(1024, 4) void mega_kernel(
    const float4* __restrict__ sorted, const unsigned* __restrict__ starts,
    const float* __restrict__ flow, const float* __restrict__ wts,
    float* __restrict__ accum, float* __restrict__ out)
{
    __shared__ unsigned uS[1024 * 16];   // 64 KB union: scan bufs / merge / ids
    float* sred = (float*)&uS[15 * 1024 + 1000];   // Phase C only
    float* sTau = (float*)&uS[16320];              // tree1-end .. Phase A
    // aux words 16316 (anyWide), 16317 (tauMax) — same lifetime as sTau

    const int tid  = threadIdx.x;
    const int lane = tid & 63;
    const int wv   = __builtin_amdgcn_readfirstlane(tid >> 6);   // 0..15
    const int is   = blockIdx.x * 64 + lane;       // sorted position

    const float4 q4 = sorted[is];
    const float qx = q4.x, qy = q4.y, qz = q4.z;
    const unsigned iorig = __float_as_uint(q4.w);
    const float q2 = fmaf(qx, qx, fmaf(qy, qy, qz * qz));
    const float analytic = 0.19072f * exp2f(0.480898f * q2);   // 8x E[d16^2]
    const float tau0 = fminf(analytic, CAPR);

    // wave min/max of the block's 64 query norms (identical in every wave)
    const float nq = sqrtf(q2);
    float nmin = nq, nmax = nq;
#pragma unroll
    for (int off = 32; off > 0; off >>= 1) {
        nmin = fminf(nmin, __shfl_xor(nmin, off));
        nmax = fmaxf(nmax, __shfl_xor(nmax, off));
    }
    // r0 from nmax (tau0 monotone in q2) — covers every lane's tau0-ball
    const float r0 = sqrtf(fminf(0.19072f * exp2f(0.480898f * nmax * nmax), CAPR));
    const int blo = nbucket(fmaxf(nmin - r0, 0.0f));
    const int bhi = nbucket(nmax + r0);
    const int W0  = __builtin_amdgcn_readfirstlane((int)starts[blo]);
    const int W1  = __builtin_amdgcn_readfirstlane((int)starts[bhi + 1]);
    const int nbt = (W1 - W0 + 7) >> 3;            // batches (pads cover tail)

    unsigned keys[KNN];
#pragma unroll
    for (int t = 0; t < KNN; ++t) keys[t] = 0xFFFFFFFFu;
    int cnt = 0;
    unsigned* buf = &uS[tid * CAPM];               // stride 15 -> spread banks

    // ================= Tau phase: every 4th super-batch (g ≡ wv mod 64) ===
    {
        float tauT = tau0;
        const float4* cb = sorted + W0;
        float4 A[BATCH], Bv[BATCH];

        auto procT = [&](const float4* C) {
#pragma unroll
            for (int q = 0; q < BATCH; ++q) {
                const float4 c = C[q];
                float dx = qx - c.x, dy = qy - c.y, dz = qz - c.z;
                float d2 = fmaf(dx, dx, fmaf(dy, dy, dz * dz));
                bool acc = d2 <= tauT;
                if (__any(acc)) {                    // wave-rare branch
                    if (acc) {
                        buf[cnt] = (__float_as_uint(d2) & 0xFFFFC000u)
                                 | __float_as_uint(c.w);   // ORIG idx
                        ++cnt;
                    }
                    if (cnt >= CAPM - 1) {
#pragma unroll 1
                        for (int t = 0; t < cnt; ++t) merge_one(keys, buf[t]);
                        cnt = 0;
                        float d16n = __uint_as_float(keys[KNN - 1] & 0xFFFFC000u);
                        tauT = fminf(tauT, fmaf(d16n, 1.0002f, 1e-6f));
                    }
                }
            }
        };

        int g = wv;
        bool hA = (g < nbt);
        if (hA) { const float4* bp = cb + 8 * g;
#pragma unroll
            for (int q = 0; q < BATCH; ++q) A[q] = bp[q]; }
        while (hA) {
            int g2 = g + 64;
            bool hB = (g2 < nbt);
            if (hB) { const float4* bp = cb + 8 * g2;
#pragma unroll
                for (int q = 0; q < BATCH; ++q) Bv[q] = bp[q]; }
            procT(A);
            if (!hB) break;
            int g3 = g2 + 64;
            bool hC = (g3 < nbt);
            if (hC) { const float4* bp = cb + 8 * g3;
#pragma unroll
                for (int q = 0; q < BATCH; ++q) A[q] = bp[q]; }
            procT(Bv);
            g = g3; hA = hC;
        }
#pragma unroll 1
        for (int t = 0; t < cnt; ++t) merge_one(keys, buf[t]);
        cnt = 0;
    }
    __syncthreads();   // bufs dead; reuse uS as transposed merge slots

    // ================= Tree merge 1 -> exact sample tau + Phase A window ==
#pragma unroll
    for (int t = 0; t < KNN; ++t) SLOT(uS, t, tid) = keys[t];
    __syncthreads();
    if (wv < 8) {
        tree_load_merge(uS, keys, tid + 512);
#pragma unroll
        for (int t = 0; t < KNN; ++t) SLOT(uS, t, tid) = keys[t];
    }
    __syncthreads();
    if (wv < 4) {
        tree_load_merge(uS, keys, tid + 256);
#pragma unroll
        for (int t = 0; t < KNN; ++t) SLOT(uS, t, tid) = keys[t];
    }
    __syncthreads();
    if (wv < 2) {
        tree_load_merge(uS, keys, tid + 128);
#pragma unroll
        for (int t = 0; t < KNN; ++t) SLOT(uS, t, tid) = keys[t];
    }
    __syncthreads();
    if (wv == 0) {
        tree_load_merge(uS, keys, tid + 64);
        const float d16 = __uint_as_float(keys[KNN - 1] & 0xFFFFC000u);
        const float tf  = fmaf(d16, 1.0002f, 1e-6f);
        // cert pass -> sample tau; fail (incl. NaN sentinel) -> radius cap.
        // fail with tau0==CAPR is covered by the window (r0=sqrt(CAPR));
        // fail with tau0<CAPR (P~e-40) forces the full-range wide path.
        const bool fail = !(tf <= tau0);
        const float tv = fail ? CAPR : tf;
        sTau[lane] = tv;
        float tm = tv;
#pragma unroll
        for (int off = 32; off > 0; off >>= 1) tm = fmaxf(tm, __shfl_xor(tm, off));
        unsigned long long bw = __ballot(fail && (analytic < CAPR));
        if (lane == 0) { uS[16316] = (bw != 0ull) ? 1u : 0u; ((float*)uS)[16317] = tm; }
    }
    __syncthreads();

    // ================= Phase A: filtered scan of the tight window =========
    float tauf = sTau[lane];
    const unsigned anyWide = __builtin_amdgcn_readfirstlane(uS[16316]);
    const float rA = sqrtf(((float*)uS)[16317]);
    int W0A, nbtA;
    if (anyWide) { W0A = 0; nbtA = NPTS / 8; }
    else {
        int bloA = nbucket(fmaxf(nmin - rA, 0.0f));
        int bhiA = nbucket(nmax + rA);
        W0A = __builtin_amdgcn_readfirstlane((int)starts[bloA]);
        int W1A = __builtin_amdgcn_readfirstlane((int)starts[bhiA + 1]);
        nbtA = (W1A - W0A + 7) >> 3;
    }
#pragma unroll
    for (int t = 0; t < KNN; ++t) keys[t] = 0xFFFFFFFFu;
    {
        const float4* cb = sorted + W0A;
        float4 A[BATCH], Bv[BATCH];

        auto procA = [&](const float4* C) {
#pragma unroll
            for (int q = 0; q < BATCH; ++q) {
                const float4 c = C[q];
                float dx = qx - c.x, dy = qy - c.y, dz = qz - c.z;
                float d2 = fmaf(dx, dx, fmaf(dy, dy, dz * dz));
                bool acc = d2 <= tauf;
                if (__any(acc)) {                    // wave-rare branch
                    if (acc) {
                        buf[cnt] = (__float_as_uint(d2) & 0xFFFFC000u)
                                 | __float_as_uint(c.w);   // ORIG idx
                        ++cnt;
                    }
                    if (cnt >= CAPM - 1) {
#pragma unroll 1
                        for (int t = 0; t < cnt; ++t) merge_one(keys, buf[t]);
                        cnt = 0;
                        float d16n = __uint_as_float(keys[KNN - 1] & 0xFFFFC000u);
                        tauf = fminf(tauf, fmaf(d16n, 1.0002f, 1e-6f));
                    }
                }
            }
        };

        int g = wv;
        bool hA = (g < nbtA);
        if (hA) { const float4* bp = cb + 8 * g;
#pragma unroll
            for (int q = 0; q < BATCH; ++q) A[q] = bp[q]; }
        while (hA) {
            int g2 = g + 16;
            bool hB = (g2 < nbtA);
            if (hB) { const float4* bp = cb + 8 * g2;
#pragma unroll
                for (int q = 0; q < BATCH; ++q) Bv[q] = bp[q]; }
            procA(A);
            if (!hB) break;
            int g3 = g2 + 16;
            bool hC = (g3 < nbtA);
            if (hC) { const float4* bp = cb + 8 * g3;
#pragma unroll
                for (int q = 0; q < BATCH; ++q) A[q] = bp[q]; }
            procA(Bv);
            g = g3; hA = hC;
        }
#pragma unroll 1
        for (int t = 0; t < cnt; ++t) merge_one(keys, buf[t]);
    }
    __syncthreads();   // scan buffers dead; reuse uS for tree 2

    // ================= Phase B: tree merge + radius -> ids (orig) =========
#pragma unroll
    for (int t = 0; t < KNN; ++t) SLOT(uS, t, tid) = keys[t];
    __syncthreads();
    if (wv < 8) {
        tree_load_merge(uS, keys, tid + 512);
#pragma unroll
        for (int t = 0; t < KNN; ++t) SLOT(uS, t, tid) = keys[t];
    }
    __syncthreads();
    if (wv < 4) {
        tree_load_merge(uS, keys, tid + 256);
#pragma unroll
        for (int t = 0; t < KNN; ++t) SLOT(uS, t, tid) = keys[t];
    }
    __syncthreads();
    if (wv < 2) {
        tree_load_merge(uS, keys, tid + 128);
#pragma unroll
        for (int t = 0; t < KNN; ++t) SLOT(uS, t, tid) = keys[t];
    }
    __syncthreads();
    if (wv == 0) {
        tree_load_merge(uS, keys, tid + 64);
        const int id0 = (int)(keys[0] & 0x3FFFu);   // nearest (self, orig idx)
#pragma unroll
        for (int t = 0; t < KNN; ++t) {
            float d2t = __uint_as_float(keys[t] & 0xFFFFC000u);
            int   j   = (int)(keys[t] & 0x3FFFu);
            SLOT(uS, t, lane) = (unsigned)((d2t > 1.0f) ? id0 : j);
        }
    }
    __syncthreads();

    // ================= Phase C: loss + reduce + finalize ==================
    {
        const int s  = wv & 7;
        const int kh = wv >> 3;
        const float* fs = flow + (size_t)s * NPTS * 3;
        const float fx = fs[3 * iorig + 0];
        const float fy = fs[3 * iorig + 1];
        const float fz = fs[3 * iorig + 2];

        float sum = 0.0f;
#pragma unroll
        for (int z = 0; z < 8; ++z) {
            int j = (int)SLOT(uS, kh * 8 + z, lane);   // conflict-free
            float dx = fx - fs[3 * j + 0];
            float dy = fy - fs[3 * j + 1];
            float dz = fz - fs[3 * j + 2];
            float sq = fmaf(dx, dx, fmaf(dy, dy, dz * dz));
            sum += (sq > 0.0f) ? sqrtf(sq) : 0.0f;
        }

        float contrib = wts[iorig] * sum;
#pragma unroll
        for (int off = 32; off > 0; off >>= 1) contrib += __shfl_down(contrib, off);
        if (lane == 0) sred[wv] = contrib;

        if (wv == 0) {                       // weight sum, once per block
            float wi = wts[iorig];
#pragma unroll
            for (int off = 32; off > 0; off >>= 1) wi += __shfl_down(wi, off);
            if (lane == 0) atomicAdd(&accum[1], wi);
        }
        __syncthreads();

        if (tid == 0) {
            float c = 0.0f;
#pragma unroll
            for (int t = 0; t < NW; ++t) c += sred[t];
            atomicAdd(&accum[0], c);
            __threadfence();
            unsigned ticket = atomicAdd((unsigned*)&accum[2], 1u);
            if (ticket == gridDim.x - 1) {   // last block finalizes
                float a  = atomicAdd(&accum[0], 0.0f);   // coherent read
                float ws = atomicAdd(&accum[1], 0.0f);
                float v  = a / (float)(KNN * SEQV);
                out[0] = (ws > 0.0f) ? (v / ws) : v;
            }
        }
    }
}

extern "C" void kernel_launch(void* const* d_in, const int* in_sizes, int n_in,
                              void* d_out, int out_size, void* d_ws, size_t ws_size,
                              hipStream_t stream)
{
    const float* pc   = (const float*)d_in[0];   // (1, N, 3)
    const float* flow = (const float*)d_in[1];   // (SEQ, N, 3)
    const float* wts  = (const float*)d_in[2];   // (N,)
    float* out = (float*)d_out;

    float*    accum  = (float*)d_ws;
    unsigned* hist   = (unsigned*)((char*)d_ws + WS_HIST);
    unsigned* starts = (unsigned*)((char*)d_ws + WS_STARTS);
    unsigned* cursor = (unsigned*)((char*)d_ws + WS_CURSOR);
    float4*   sorted = (float4*)  ((char*)d_ws + WS_SORTED);

    hipMemsetAsync(d_ws, 0, 1280, stream);       // accum + hist

    hist_kernel   <<<NPTS / 1024, 1024, 0, stream>>>(pc, hist);
    prefix_kernel <<<1, NBKT, 0, stream>>>(hist, starts, cursor);
    scatter_kernel<<<NPTS / 1024, 1024, 0, stream>>>(pc, cursor, sorted);
    mega_kernel   <<<NPTS / 64, 1024, 0, stream>>>(sorted, starts, flow, wts, accum, out);
}